// Round 1
// baseline (573.465 us; speedup 1.0000x reference)
//
#include <hip/hip_runtime.h>

#define IN_F   4096
#define OUT_F  4096
#define BS     64      // block size of the sparsity pattern
#define NB     64      // number of 64-blocks along each weight dim
#define N_TOK  8192
#define TM     128     // token-tile per workgroup
#define TN     64      // output-feature tile per workgroup (= one block)

// ---------------------------------------------------------------------------
// Kernel 1: build block-sparse metadata from the (block-constant) mask.
// One workgroup of 64 threads per weight block-row. Deterministic (ballot +
// prefix popcount, no atomics).
// ws layout: int counts[NB]; int cols[NB*NB];
// ---------------------------------------------------------------------------
__global__ void build_meta_kernel(const float* __restrict__ mask,
                                  int* __restrict__ counts,
                                  int* __restrict__ cols) {
    int br = blockIdx.x;        // weight block-row  (output block)
    int bc = threadIdx.x;       // weight block-col  (input block), 0..63
    // mask is constant within each 64x64 block -> probe one element
    float v = mask[(size_t)(br * BS) * IN_F + (size_t)bc * BS];
    unsigned long long ball = __ballot(v != 0.0f);
    if (v != 0.0f) {
        int pos = __popcll(ball & ((1ull << bc) - 1ull));
        cols[br * NB + pos] = bc;
    }
    if (bc == 0) counts[br] = __popcll(ball);
}

// ---------------------------------------------------------------------------
// Kernel 2: block-sparse GEMM  out = x @ (W o mask)^T + bias
//   out[m][o] = sum_{kept kb} sum_i x[m][kb*64+i] * W[o][kb*64+i]  + bias[o]
// Workgroup: 256 threads, computes TM x TN = 128 x 64 output tile.
// Each thread: 8x4 register micro-tile.
// ---------------------------------------------------------------------------
__global__ __launch_bounds__(256)
void bsr_linear_kernel(const float* __restrict__ x,
                       const float* __restrict__ w,
                       const float* __restrict__ bias,
                       const int*   __restrict__ counts,
                       const int*   __restrict__ cols,
                       float* __restrict__ out) {
    __shared__ float xs[TM][BS + 1];   // +1 pad: break power-of-2 bank stride
    __shared__ float ws[BS][BS + 1];

    const int br    = blockIdx.x;      // output block (0..63)
    const int mt    = blockIdx.y;      // token tile   (0..63)
    const int tid   = threadIdx.x;
    const int tx    = tid & 15;        // 16 col-groups of 4 outputs
    const int ty    = tid >> 4;        // 16 row-groups of 8 tokens

    const int obase = br * BS;
    const int mbase = mt * TM;

    float acc[8][4];
#pragma unroll
    for (int r = 0; r < 8; ++r)
#pragma unroll
        for (int c = 0; c < 4; ++c) acc[r][c] = 0.0f;

    const int  cnt  = counts[br];
    const int* colp = cols + br * NB;

    for (int k = 0; k < cnt; ++k) {
        const int kbase = colp[k] * BS;

        // ---- stage W block: 64x64 floats = 1024 float4, 4 per thread ----
#pragma unroll
        for (int l = 0; l < 4; ++l) {
            int idx  = tid + l * 256;          // float4 index 0..1023
            int row  = idx >> 4;               // 0..63
            int col4 = idx & 15;               // 0..15
            float4 v = *(const float4*)&w[(size_t)(obase + row) * IN_F + kbase + col4 * 4];
            ws[row][col4 * 4 + 0] = v.x;
            ws[row][col4 * 4 + 1] = v.y;
            ws[row][col4 * 4 + 2] = v.z;
            ws[row][col4 * 4 + 3] = v.w;
        }
        // ---- stage x tile: 128x64 floats = 2048 float4, 8 per thread ----
#pragma unroll
        for (int l = 0; l < 8; ++l) {
            int idx  = tid + l * 256;          // float4 index 0..2047
            int row  = idx >> 4;               // 0..127
            int col4 = idx & 15;
            float4 v = *(const float4*)&x[(size_t)(mbase + row) * IN_F + kbase + col4 * 4];
            xs[row][col4 * 4 + 0] = v.x;
            xs[row][col4 * 4 + 1] = v.y;
            xs[row][col4 * 4 + 2] = v.z;
            xs[row][col4 * 4 + 3] = v.w;
        }
        __syncthreads();

        // ---- compute: outer product over the 64-wide K slice ----
#pragma unroll 4
        for (int i = 0; i < BS; ++i) {
            float xv[8], wv[4];
#pragma unroll
            for (int r = 0; r < 8; ++r) xv[r] = xs[ty * 8 + r][i];
#pragma unroll
            for (int c = 0; c < 4; ++c) wv[c] = ws[tx * 4 + c][i];
#pragma unroll
            for (int r = 0; r < 8; ++r)
#pragma unroll
                for (int c = 0; c < 4; ++c)
                    acc[r][c] = fmaf(xv[r], wv[c], acc[r][c]);
        }
        __syncthreads();
    }

    // ---- epilogue: add bias, float4 stores ----
    float4 b4 = *(const float4*)&bias[obase + tx * 4];
#pragma unroll
    for (int r = 0; r < 8; ++r) {
        float4 o4;
        o4.x = acc[r][0] + b4.x;
        o4.y = acc[r][1] + b4.y;
        o4.z = acc[r][2] + b4.z;
        o4.w = acc[r][3] + b4.w;
        *(float4*)&out[(size_t)(mbase + ty * 8 + r) * OUT_F + obase + tx * 4] = o4;
    }
}

extern "C" void kernel_launch(void* const* d_in, const int* in_sizes, int n_in,
                              void* d_out, int out_size, void* d_ws, size_t ws_size,
                              hipStream_t stream) {
    const float* x    = (const float*)d_in[0];
    const float* w    = (const float*)d_in[1];
    const float* bias = (const float*)d_in[2];
    const float* mask = (const float*)d_in[3];
    float* out = (float*)d_out;

    int* counts = (int*)d_ws;            // NB ints
    int* cols   = counts + NB;           // NB*NB ints

    build_meta_kernel<<<NB, 64, 0, stream>>>(mask, counts, cols);

    dim3 grid(NB, N_TOK / TM);           // 64 x 64 workgroups
    bsr_linear_kernel<<<grid, 256, 0, stream>>>(x, w, bias, counts, cols, out);
}

// Round 2
// 167.884 us; speedup vs baseline: 3.4158x; 3.4158x over previous
//
#include <hip/hip_runtime.h>

#define IN_F   4096
#define OUT_F  4096
#define BS     64      // sparsity block size
#define NB     64      // blocks per weight dim
#define N_TOK  8192
#define TM     128     // token tile per workgroup
#define BK     64      // K-slice = one sparsity block

typedef __attribute__((ext_vector_type(8))) short     bf16x8;
typedef __attribute__((ext_vector_type(8))) unsigned short u16x8;
typedef __attribute__((ext_vector_type(4))) float     f32x4;

// ---------------------------------------------------------------------------
// Kernel 1: block-sparse metadata from the block-constant mask (deterministic)
// ---------------------------------------------------------------------------
__global__ void build_meta_kernel(const float* __restrict__ mask,
                                  int* __restrict__ counts,
                                  int* __restrict__ cols) {
    int br = blockIdx.x;
    int bc = threadIdx.x;
    float v = mask[(size_t)(br * BS) * IN_F + (size_t)bc * BS];
    unsigned long long ball = __ballot(v != 0.0f);
    if (v != 0.0f) {
        int pos = __popcll(ball & ((1ull << bc) - 1ull));
        cols[br * NB + pos] = bc;
    }
    if (bc == 0) counts[br] = __popcll(ball);
}

// split fp32 -> bf16 hi + bf16 lo (RNE both);  x ~= hi + lo, residual ~2^-17|x|
__device__ __forceinline__ void cvt_split8(const float* v, u16x8& hv, u16x8& lv) {
#pragma unroll
    for (int j = 0; j < 8; ++j) {
        unsigned u  = __float_as_uint(v[j]);
        unsigned r  = u + 0x7FFFu + ((u >> 16) & 1u);
        unsigned short h = (unsigned short)(r >> 16);
        float hf = __uint_as_float(((unsigned)h) << 16);
        float l  = v[j] - hf;
        unsigned ul = __float_as_uint(l);
        unsigned rl = ul + 0x7FFFu + ((ul >> 16) & 1u);
        hv[j] = h;
        lv[j] = (unsigned short)(rl >> 16);
    }
}

// ---------------------------------------------------------------------------
// Kernel 2: block-sparse GEMM via split-bf16 MFMA.
//   out[m][o] = sum_kept_kb sum_i x[m][kb*64+i] * W[o][kb*64+i] + bias[o]
// WG: 256 thr (4 waves). Tile: TM(128) x 64 outputs. Wave: 32 x 64.
// LDS bf16 tiles XOR-swizzled in 16B slots: slot ^= (row & 7).
// ---------------------------------------------------------------------------
__global__ __launch_bounds__(256, 3)
void bsr_mfma_kernel(const float* __restrict__ x,
                     const float* __restrict__ w,
                     const float* __restrict__ bias,
                     const int*   __restrict__ counts,
                     const int*   __restrict__ cols,
                     float* __restrict__ out) {
    __shared__ unsigned short xs_hi[TM * BK];   // [row][k] 16B-slot swizzled
    __shared__ unsigned short xs_lo[TM * BK];
    __shared__ unsigned short ws_hi[BS * BK];
    __shared__ unsigned short ws_lo[BS * BK];

    const int mt   = blockIdx.x;      // token tile (fastest -> W stays in L2)
    const int br   = blockIdx.y;      // output block-row
    const int tid  = threadIdx.x;
    const int lane = tid & 63;
    const int wv   = tid >> 6;        // wave id 0..3
    const int fr   = lane & 15;       // fragment row (A) / col (B)
    const int kg   = lane >> 4;       // k-group 0..3

    const int mbase = mt * TM;
    const int obase = br * BS;

    const int  cnt  = counts[br];
    const int* colp = cols + br * NB;

    f32x4 acc[2][4];
#pragma unroll
    for (int a = 0; a < 2; ++a)
#pragma unroll
        for (int b = 0; b < 4; ++b) acc[a][b] = (f32x4)0.0f;

    for (int kb = 0; kb < cnt; ++kb) {
        const int kbase = colp[kb] * BS;

        // ---- stage x tile: 128x64 fp32 -> bf16 hi/lo. 1024 8-elem groups ----
#pragma unroll
        for (int l = 0; l < 4; ++l) {
            int g = tid + l * 256;
            int row = g >> 3, slot = g & 7;
            const float* src = x + (size_t)(mbase + row) * IN_F + kbase + slot * 8;
            float4 v0 = *(const float4*)(src);
            float4 v1 = *(const float4*)(src + 4);
            float v[8] = {v0.x, v0.y, v0.z, v0.w, v1.x, v1.y, v1.z, v1.w};
            u16x8 hv, lv;
            cvt_split8(v, hv, lv);
            int dst = row * BK + ((slot ^ (row & 7)) << 3);
            *(u16x8*)&xs_hi[dst] = hv;
            *(u16x8*)&xs_lo[dst] = lv;
        }
        // ---- stage W block: 64x64 fp32 -> bf16 hi/lo. 512 groups ----
#pragma unroll
        for (int l = 0; l < 2; ++l) {
            int g = tid + l * 256;
            int row = g >> 3, slot = g & 7;
            const float* src = w + (size_t)(obase + row) * IN_F + kbase + slot * 8;
            float4 v0 = *(const float4*)(src);
            float4 v1 = *(const float4*)(src + 4);
            float v[8] = {v0.x, v0.y, v0.z, v0.w, v1.x, v1.y, v1.z, v1.w};
            u16x8 hv, lv;
            cvt_split8(v, hv, lv);
            int dst = row * BK + ((slot ^ (row & 7)) << 3);
            *(u16x8*)&ws_hi[dst] = hv;
            *(u16x8*)&ws_lo[dst] = lv;
        }
        __syncthreads();

        // ---- MFMA: 2 K-steps of 32; 3 split passes (hh, hl, lh) ----
#pragma unroll
        for (int ks = 0; ks < 2; ++ks) {
            bf16x8 ah[2], al[2], bh[4], bl[4];
#pragma unroll
            for (int mr = 0; mr < 2; ++mr) {
                int row  = wv * 32 + mr * 16 + fr;
                int slot = (ks * 4 + kg) ^ (row & 7);
                int off  = row * BK + (slot << 3);
                ah[mr] = *(bf16x8*)&xs_hi[off];
                al[mr] = *(bf16x8*)&xs_lo[off];
            }
#pragma unroll
            for (int nr = 0; nr < 4; ++nr) {
                int row  = nr * 16 + fr;
                int slot = (ks * 4 + kg) ^ (row & 7);
                int off  = row * BK + (slot << 3);
                bh[nr] = *(bf16x8*)&ws_hi[off];
                bl[nr] = *(bf16x8*)&ws_lo[off];
            }
#pragma unroll
            for (int mr = 0; mr < 2; ++mr)
#pragma unroll
                for (int nr = 0; nr < 4; ++nr) {
                    acc[mr][nr] = __builtin_amdgcn_mfma_f32_16x16x32_bf16(
                        ah[mr], bh[nr], acc[mr][nr], 0, 0, 0);
                    acc[mr][nr] = __builtin_amdgcn_mfma_f32_16x16x32_bf16(
                        ah[mr], bl[nr], acc[mr][nr], 0, 0, 0);
                    acc[mr][nr] = __builtin_amdgcn_mfma_f32_16x16x32_bf16(
                        al[mr], bh[nr], acc[mr][nr], 0, 0, 0);
                }
        }
        __syncthreads();
    }

    // ---- epilogue: bias + fp32 stores.  C/D: col=lane&15, row=(lane>>4)*4+r ----
#pragma unroll
    for (int nr = 0; nr < 4; ++nr) {
        float bv = bias[obase + nr * 16 + fr];
#pragma unroll
        for (int mr = 0; mr < 2; ++mr) {
#pragma unroll
            for (int r = 0; r < 4; ++r) {
                int m = mbase + wv * 32 + mr * 16 + kg * 4 + r;
                out[(size_t)m * OUT_F + obase + nr * 16 + fr] = acc[mr][nr][r] + bv;
            }
        }
    }
}

extern "C" void kernel_launch(void* const* d_in, const int* in_sizes, int n_in,
                              void* d_out, int out_size, void* d_ws, size_t ws_size,
                              hipStream_t stream) {
    const float* x    = (const float*)d_in[0];
    const float* w    = (const float*)d_in[1];
    const float* bias = (const float*)d_in[2];
    const float* mask = (const float*)d_in[3];
    float* out = (float*)d_out;

    int* counts = (int*)d_ws;            // NB ints
    int* cols   = counts + NB;           // NB*NB ints

    build_meta_kernel<<<NB, 64, 0, stream>>>(mask, counts, cols);

    dim3 grid(N_TOK / TM, NB);           // x = token tile (fast), y = block-row
    bsr_mfma_kernel<<<grid, 256, 0, stream>>>(x, w, bias, counts, cols, out);
}